// Round 1
// baseline (313.498 us; speedup 1.0000x reference)
//
#include <hip/hip_runtime.h>

typedef short short8 __attribute__((ext_vector_type(8)));
typedef float f32x4 __attribute__((ext_vector_type(4)));
typedef unsigned int uint4v __attribute__((ext_vector_type(4)));

__device__ __forceinline__ short f2bf(float f) {
  unsigned u = __builtin_bit_cast(unsigned, f);
  u += 0x7fffu + ((u >> 16) & 1u);          // RNE
  return (short)(u >> 16);
}
__device__ __forceinline__ float bf2f(short s) {
  unsigned u = ((unsigned)(unsigned short)s) << 16;
  return __builtin_bit_cast(float, u);
}

#define BM 128
#define BN 128
#define BKS 32
#define KPD 40   // padded K stride (bf16 elems): 80B rows, 16B aligned, 2-way bank (free)

// ---------------- Projection GEMM: P = X @ W + b, bf16 out -------------------
// z=0: Q -> qbuf [NS][544] at cols h*34+2+j ; z=1: K -> kp [NS][512]; z=2: V -> vp
__global__ __launch_bounds__(256) void proj_kernel(
    const float* __restrict__ Q, const float* __restrict__ Kin, const float* __restrict__ Vin,
    const float* __restrict__ WQ, const float* __restrict__ WK, const float* __restrict__ WV,
    const float* __restrict__ bQ, const float* __restrict__ bK, const float* __restrict__ bV,
    short* __restrict__ qbuf, short* __restrict__ kp, short* __restrict__ vp)
{
  const int z = blockIdx.z;
  const float* X    = (z == 0) ? Q  : (z == 1) ? Kin : Vin;
  const float* W    = (z == 0) ? WQ : (z == 1) ? WK  : WV;
  const float* bias = (z == 0) ? bQ : (z == 1) ? bK  : bV;

  const int row0 = blockIdx.y * BM;      // in [0, 32768)
  const int col0 = blockIdx.x * BN;      // in [0, 512)

  __shared__ short a_lds[BM * KPD];
  __shared__ short b_lds[BN * KPD];      // B^T layout: [n-col][k]

  const int tid  = threadIdx.x;
  const int lane = tid & 63;
  const int wv   = tid >> 6;
  const int wr = wv >> 1, wc = wv & 1;
  const int fr = lane & 15, fg = lane >> 4;

  f32x4 acc[4][4];
#pragma unroll
  for (int i = 0; i < 4; ++i)
#pragma unroll
    for (int j = 0; j < 4; ++j) acc[i][j] = (f32x4){0.f, 0.f, 0.f, 0.f};

  const int ar = tid >> 1, ah = tid & 1;       // A staging: row, 16-float half
  const int bcol = tid & 127, bseg = tid >> 7; // B staging: col, 16-k segment

  for (int k0 = 0; k0 < 512; k0 += BKS) {
    __syncthreads();
    { // stage A tile [128 rows][32 k], fp32 -> bf16
      const f32x4* ap = (const f32x4*)(X + (size_t)(row0 + ar) * 512 + k0 + ah * 16);
      f32x4 f0 = ap[0], f1 = ap[1], f2 = ap[2], f3 = ap[3];
      short8 s0, s1;
#pragma unroll
      for (int i = 0; i < 4; ++i) {
        s0[i] = f2bf(f0[i]); s0[i + 4] = f2bf(f1[i]);
        s1[i] = f2bf(f2[i]); s1[i + 4] = f2bf(f3[i]);
      }
      short8* dst = (short8*)&a_lds[ar * KPD + ah * 16];
      dst[0] = s0; dst[1] = s1;
    }
    { // stage B^T tile: column bcol, 16 k values (coalesced across lanes)
      const float* bp = W + (size_t)(k0 + bseg * 16) * 512 + col0 + bcol;
      short8 s0, s1;
#pragma unroll
      for (int i = 0; i < 8; ++i) s0[i] = f2bf(bp[(size_t)i * 512]);
#pragma unroll
      for (int i = 0; i < 8; ++i) s1[i] = f2bf(bp[(size_t)(i + 8) * 512]);
      short8* dst = (short8*)&b_lds[bcol * KPD + bseg * 16];
      dst[0] = s0; dst[1] = s1;
    }
    __syncthreads();

    short8 af[4], bf[4];
#pragma unroll
    for (int mi = 0; mi < 4; ++mi)
      af[mi] = *(const short8*)&a_lds[(wr * 64 + mi * 16 + fr) * KPD + fg * 8];
#pragma unroll
    for (int ni = 0; ni < 4; ++ni)
      bf[ni] = *(const short8*)&b_lds[(wc * 64 + ni * 16 + fr) * KPD + fg * 8];
#pragma unroll
    for (int mi = 0; mi < 4; ++mi)
#pragma unroll
      for (int ni = 0; ni < 4; ++ni)
        acc[mi][ni] = __builtin_amdgcn_mfma_f32_16x16x32_bf16(af[mi], bf[ni], acc[mi][ni], 0, 0, 0);
  }

#pragma unroll
  for (int ni = 0; ni < 4; ++ni) {
    const int gc = col0 + wc * 64 + ni * 16 + fr;
    const float bv = bias[gc];
#pragma unroll
    for (int mi = 0; mi < 4; ++mi) {
#pragma unroll
      for (int r = 0; r < 4; ++r) {
        const int gr = row0 + wr * 64 + mi * 16 + fg * 4 + r;   // C: col=lane&15, row=(lane>>4)*4+reg
        const short b = f2bf(acc[mi][ni][r] + bv);
        if (z == 0) {
          const int h = gc >> 5, j = gc & 31;
          qbuf[(size_t)gr * 544 + h * 34 + 2 + j] = b;
        } else if (z == 1) {
          kp[(size_t)gr * 512 + gc] = b;
        } else {
          vp[(size_t)gr * 512 + gc] = b;
        }
      }
    }
  }
}

// ---------------- pos columns of qbuf --------------------------------------
__global__ __launch_bounds__(256) void fillpos_kernel(
    const float* __restrict__ pos, short* __restrict__ qbuf)
{
  const int i = blockIdx.x * 256 + threadIdx.x;   // 0..32767 == n*8192+s
  const short b0 = f2bf(pos[(size_t)i * 2]);
  const short b1 = f2bf(pos[(size_t)i * 2 + 1]);
  short* row = qbuf + (size_t)i * 544;
#pragma unroll
  for (int h = 0; h < 16; ++h) { row[h * 34] = b0; row[h * 34 + 1] = b1; }
}

// ---------------- LN + ktv accumulation ------------------------------------
// internal LDS row order: [ln0..ln31, pos0, pos1, garbage...]; remap on atomic write.
#define SC 256
#define TP 264   // 528B row stride: 16B aligned, banks step 4 -> 2-way (free)

__global__ __launch_bounds__(256) void ktv_kernel(
    const short* __restrict__ kp, const short* __restrict__ vp,
    const float* __restrict__ pos,
    const float* __restrict__ lnwK, const float* __restrict__ lnbK,
    const float* __restrict__ lnwV, const float* __restrict__ lnbV,
    float* __restrict__ ktv)
{
  const int nh = blockIdx.y;
  const int n = nh >> 4, h = nh & 15;
  const int s0 = blockIdx.x * SC;
  const int tid = threadIdx.x;

  __shared__ short klds[48 * TP];   // transposed: [d][s_local]
  __shared__ short vlds[48 * TP];
  __shared__ float lw[2][32], lb[2][32];

  if (tid < 32) {
    lw[0][tid] = lnwK[h * 32 + tid]; lb[0][tid] = lnbK[h * 32 + tid];
    lw[1][tid] = lnwV[h * 32 + tid]; lb[1][tid] = lnbV[h * 32 + tid];
  }
  __syncthreads();

  const size_t rowix = (size_t)n * 8192 + (s0 + tid);
  { // K side: load 32 bf16, LN in fp32, write transposed
    const short8* src = (const short8*)(kp + rowix * 512 + h * 32);
    short8 r0 = src[0], r1 = src[1], r2 = src[2], r3 = src[3];
    float x[32];
#pragma unroll
    for (int i = 0; i < 8; ++i) { x[i] = bf2f(r0[i]); x[8+i] = bf2f(r1[i]); x[16+i] = bf2f(r2[i]); x[24+i] = bf2f(r3[i]); }
    float mu = 0.f;
#pragma unroll
    for (int i = 0; i < 32; ++i) mu += x[i];
    mu *= (1.f / 32.f);
    float var = 0.f;
#pragma unroll
    for (int i = 0; i < 32; ++i) { float d = x[i] - mu; var += d * d; }
    var *= (1.f / 32.f);
    const float rstd = rsqrtf(var + 1e-5f);
#pragma unroll
    for (int d = 0; d < 32; ++d)
      klds[d * TP + tid] = f2bf((x[d] - mu) * rstd * lw[0][d] + lb[0][d]);
  }
  { // V side
    const short8* src = (const short8*)(vp + rowix * 512 + h * 32);
    short8 r0 = src[0], r1 = src[1], r2 = src[2], r3 = src[3];
    float x[32];
#pragma unroll
    for (int i = 0; i < 8; ++i) { x[i] = bf2f(r0[i]); x[8+i] = bf2f(r1[i]); x[16+i] = bf2f(r2[i]); x[24+i] = bf2f(r3[i]); }
    float mu = 0.f;
#pragma unroll
    for (int i = 0; i < 32; ++i) mu += x[i];
    mu *= (1.f / 32.f);
    float var = 0.f;
#pragma unroll
    for (int i = 0; i < 32; ++i) { float d = x[i] - mu; var += d * d; }
    var *= (1.f / 32.f);
    const float rstd = rsqrtf(var + 1e-5f);
#pragma unroll
    for (int d = 0; d < 32; ++d)
      vlds[d * TP + tid] = f2bf((x[d] - mu) * rstd * lw[1][d] + lb[1][d]);
  }
  { // pos rows (internal rows 32,33)
    const short p0 = f2bf(pos[rowix * 2]);
    const short p1 = f2bf(pos[rowix * 2 + 1]);
    klds[32 * TP + tid] = p0; klds[33 * TP + tid] = p1;
    vlds[32 * TP + tid] = p0; vlds[33 * TP + tid] = p1;
  }
  __syncthreads();

  const int wv = tid >> 6, lane = tid & 63;
  if (wv < 3) {                        // wave wv owns d-tile rows [wv*16, wv*16+16)
    const int fr = lane & 15, fg = lane >> 4;
    f32x4 acc[3];
#pragma unroll
    for (int i = 0; i < 3; ++i) acc[i] = (f32x4){0.f, 0.f, 0.f, 0.f};
    for (int kk = 0; kk < SC; kk += 32) {
      short8 a = *(const short8*)&klds[(wv * 16 + fr) * TP + kk + fg * 8];
#pragma unroll
      for (int ni = 0; ni < 3; ++ni) {
        short8 b = *(const short8*)&vlds[(ni * 16 + fr) * TP + kk + fg * 8];
        acc[ni] = __builtin_amdgcn_mfma_f32_16x16x32_bf16(a, b, acc[ni], 0, 0, 0);
      }
    }
#pragma unroll
    for (int ni = 0; ni < 3; ++ni) {
      const int ei = ni * 16 + fr;
      if (ei < 34) {
        const int er = (ei < 32) ? ei + 2 : ei - 32;   // internal -> reference order
#pragma unroll
        for (int r = 0; r < 4; ++r) {
          const int di = wv * 16 + fg * 4 + r;
          if (di < 34) {
            const int dr = (di < 32) ? di + 2 : di - 32;
            atomicAdd(&ktv[((size_t)nh * 34 + dr) * 34 + er], acc[ni][r]);
          }
        }
      }
    }
  }
}

// ---------------- M[n][c][o] = sum_e ktv[n,h,d,e]/S * fcW[o][h*34+e] --------
__global__ __launch_bounds__(256) void mmk_kernel(
    const float* __restrict__ ktv, const float* __restrict__ fcW,
    short* __restrict__ M)
{
  const int n = blockIdx.y;
  const int c = blockIdx.x;             // 0..543
  const int h = c / 34, d = c - h * 34;
  __shared__ float row[34];
  if (threadIdx.x < 34)
    row[threadIdx.x] = ktv[(((size_t)n * 16 + h) * 34 + d) * 34 + threadIdx.x] * (1.0f / 8192.0f);
  __syncthreads();
  for (int o = threadIdx.x; o < 512; o += 256) {
    const float* wr = fcW + (size_t)o * 544 + h * 34;
    float acc = 0.f;
#pragma unroll
    for (int e = 0; e < 34; ++e) acc += row[e] * wr[e];
    M[((size_t)n * 544 + c) * 512 + o] = f2bf(acc);
  }
}

// ---------------- final GEMM: out[n] = qbuf[n] @ M[n] + fc_b ----------------
__global__ __launch_bounds__(256) void fgemm_kernel(
    const short* __restrict__ qbuf, const short* __restrict__ M,
    const float* __restrict__ fcb, float* __restrict__ out)
{
  const int n = blockIdx.z;
  const int row0 = blockIdx.y * BM;     // within 8192
  const int col0 = blockIdx.x * BN;     // within 512

  const short* A = qbuf + (size_t)n * 8192 * 544;
  const short* B = M + (size_t)n * 544 * 512;

  __shared__ short a_lds[BM * KPD];
  __shared__ short b_lds[BN * KPD];

  const int tid = threadIdx.x;
  const int lane = tid & 63, wv = tid >> 6;
  const int wr = wv >> 1, wc = wv & 1;
  const int fr = lane & 15, fg = lane >> 4;

  f32x4 acc[4][4];
#pragma unroll
  for (int i = 0; i < 4; ++i)
#pragma unroll
    for (int j = 0; j < 4; ++j) acc[i][j] = (f32x4){0.f, 0.f, 0.f, 0.f};

  const int ar = tid >> 1, ah = tid & 1;
  const int bcol = tid & 127, bseg = tid >> 7;

  for (int k0 = 0; k0 < 544; k0 += BKS) {   // 17 exact steps
    __syncthreads();
    { // A already bf16: straight 16B copies
      const uint4v* ap = (const uint4v*)(A + (size_t)(row0 + ar) * 544 + k0 + ah * 16);
      uint4v v0 = ap[0], v1 = ap[1];
      uint4v* dst = (uint4v*)&a_lds[ar * KPD + ah * 16];
      dst[0] = v0; dst[1] = v1;
    }
    { // B^T staging, bf16 column gather (coalesced across lanes)
      const short* bp = B + (size_t)(k0 + bseg * 16) * 512 + col0 + bcol;
      short8 s0, s1;
#pragma unroll
      for (int i = 0; i < 8; ++i) s0[i] = bp[(size_t)i * 512];
#pragma unroll
      for (int i = 0; i < 8; ++i) s1[i] = bp[(size_t)(i + 8) * 512];
      short8* dst = (short8*)&b_lds[bcol * KPD + bseg * 16];
      dst[0] = s0; dst[1] = s1;
    }
    __syncthreads();

    short8 af[4], bf[4];
#pragma unroll
    for (int mi = 0; mi < 4; ++mi)
      af[mi] = *(const short8*)&a_lds[(wr * 64 + mi * 16 + fr) * KPD + fg * 8];
#pragma unroll
    for (int ni = 0; ni < 4; ++ni)
      bf[ni] = *(const short8*)&b_lds[(wc * 64 + ni * 16 + fr) * KPD + fg * 8];
#pragma unroll
    for (int mi = 0; mi < 4; ++mi)
#pragma unroll
      for (int ni = 0; ni < 4; ++ni)
        acc[mi][ni] = __builtin_amdgcn_mfma_f32_16x16x32_bf16(af[mi], bf[ni], acc[mi][ni], 0, 0, 0);
  }

#pragma unroll
  for (int ni = 0; ni < 4; ++ni) {
    const int gc = col0 + wc * 64 + ni * 16 + fr;
    const float bv = fcb[gc];
#pragma unroll
    for (int mi = 0; mi < 4; ++mi)
#pragma unroll
      for (int r = 0; r < 4; ++r) {
        const int gr = row0 + wr * 64 + mi * 16 + fg * 4 + r;
        out[((size_t)n * 8192 + gr) * 512 + gc] = acc[mi][ni][r] + bv;
      }
  }
}

// ---------------------------------------------------------------------------
extern "C" void kernel_launch(void* const* d_in, const int* in_sizes, int n_in,
                              void* d_out, int out_size, void* d_ws, size_t ws_size,
                              hipStream_t stream) {
  const float* Q    = (const float*)d_in[0];
  const float* Kin  = (const float*)d_in[1];
  const float* Vin  = (const float*)d_in[2];
  const float* pos  = (const float*)d_in[3];
  const float* WQ   = (const float*)d_in[4];
  const float* WK   = (const float*)d_in[5];
  const float* WV   = (const float*)d_in[6];
  const float* bQ   = (const float*)d_in[7];
  const float* bK   = (const float*)d_in[8];
  const float* bV   = (const float*)d_in[9];
  const float* lnwK = (const float*)d_in[10];
  const float* lnbK = (const float*)d_in[11];
  const float* lnwV = (const float*)d_in[12];
  const float* lnbV = (const float*)d_in[13];
  const float* fcW  = (const float*)d_in[14];
  const float* fcb  = (const float*)d_in[15];

  char* ws = (char*)d_ws;
  const size_t QBUF_B = (size_t)4 * 8192 * 544 * 2;   // 35,651,584
  const size_t KP_B   = (size_t)4 * 8192 * 512 * 2;   // 33,554,432
  const size_t KTV_B  = (size_t)64 * 34 * 34 * 4;     //    295,936
  short* qbuf = (short*)ws;
  short* kp   = (short*)(ws + QBUF_B);
  short* vp   = (short*)(ws + QBUF_B + KP_B);
  float* ktv  = (float*)(ws + QBUF_B + 2 * KP_B);
  short* Mb   = (short*)(ws + QBUF_B + 2 * KP_B + KTV_B);

  hipMemsetAsync(ktv, 0, KTV_B, stream);
  hipLaunchKernelGGL(proj_kernel, dim3(4, 256, 3), dim3(256), 0, stream,
                     Q, Kin, Vin, WQ, WK, WV, bQ, bK, bV, qbuf, kp, vp);
  hipLaunchKernelGGL(fillpos_kernel, dim3(128), dim3(256), 0, stream, pos, qbuf);
  hipLaunchKernelGGL(ktv_kernel, dim3(32, 64), dim3(256), 0, stream,
                     kp, vp, pos, lnwK, lnbK, lnwV, lnbV, ktv);
  hipLaunchKernelGGL(mmk_kernel, dim3(544, 4), dim3(256), 0, stream, ktv, fcW, Mb);
  hipLaunchKernelGGL(fgemm_kernel, dim3(4, 64, 4), dim3(256), 0, stream,
                     qbuf, Mb, fcb, (float*)d_out);
}

// Round 3
// 289.020 us; speedup vs baseline: 1.0847x; 1.0847x over previous
//
#include <hip/hip_runtime.h>
#include <hip/hip_bf16.h>

typedef short short8 __attribute__((ext_vector_type(8)));
typedef float f32x4 __attribute__((ext_vector_type(4)));
typedef unsigned int uint4v __attribute__((ext_vector_type(4)));

__device__ __forceinline__ short f2bf(float f) {
  unsigned u = __builtin_bit_cast(unsigned, f);
  u += 0x7fffu + ((u >> 16) & 1u);          // RNE
  return (short)(u >> 16);
}
__device__ __forceinline__ float bf2f(short s) {
  unsigned u = ((unsigned)(unsigned short)s) << 16;
  return __builtin_bit_cast(float, u);
}
// packed pair conversion -> v_cvt_pk_bf16_f32 (compiler handles)
__device__ __forceinline__ unsigned pk2(float a, float b) {
  __hip_bfloat162 h = __float22bfloat162_rn(float2{a, b});
  unsigned u;
  __builtin_memcpy(&u, &h, 4);
  return u;
}
// async global->LDS, 16B per lane; lds dest = wave-uniform base + lane*16
__device__ __forceinline__ void gl_lds16(const void* g, void* l) {
  __builtin_amdgcn_global_load_lds(
      (const __attribute__((address_space(1))) unsigned int*)g,
      (__attribute__((address_space(3))) unsigned int*)l, 16, 0, 0);
}

#define QSTRIDE 576   // 544 data cols + 32 zero pad (K-loop multiple of 32; 16B-aligned rows)

// ---------------- W transpose + bf16 convert: Wt[z][n][k] -------------------
__global__ __launch_bounds__(256) void wt_kernel(
    const float* __restrict__ WQ, const float* __restrict__ WK, const float* __restrict__ WV,
    short* __restrict__ Wt)
{
  const int z = blockIdx.z;
  const float* W = (z == 0) ? WQ : (z == 1) ? WK : WV;
  short* o = Wt + (size_t)z * 512 * 512;
  __shared__ short t[64][65];
  const int k0 = blockIdx.y * 64, n0 = blockIdx.x * 64;
  const int c = threadIdx.x & 63, rb = threadIdx.x >> 6;
#pragma unroll
  for (int p = 0; p < 16; ++p) {
    const int kk = p * 4 + rb;
    t[kk][c] = f2bf(W[(size_t)(k0 + kk) * 512 + n0 + c]);
  }
  __syncthreads();
#pragma unroll
  for (int p = 0; p < 16; ++p) {
    const int nn = p * 4 + rb;
    o[(size_t)(n0 + nn) * 512 + k0 + c] = t[c][nn];
  }
}

// ---------------- Projection GEMM: P = X @ W + b, bf16 out ------------------
// z=0: Q -> qbuf [NS][576] at cols h*34+2+j ; z=1: K -> kp [NS][512]; z=2: V -> vp
__global__ __launch_bounds__(256) void proj_kernel(
    const float* __restrict__ Q, const float* __restrict__ Kin, const float* __restrict__ Vin,
    const short* __restrict__ Wt,
    const float* __restrict__ bQ, const float* __restrict__ bK, const float* __restrict__ bV,
    short* __restrict__ qbuf, short* __restrict__ kp, short* __restrict__ vp)
{
  const int z = blockIdx.z;
  const float* X    = (z == 0) ? Q  : (z == 1) ? Kin : Vin;
  const float* bias = (z == 0) ? bQ : (z == 1) ? bK  : bV;
  const short* Wz   = Wt + (size_t)z * 512 * 512;

  const int row0 = blockIdx.y * 128;
  const int col0 = blockIdx.x * 128;

  __shared__ short a_lds[128 * 32];
  __shared__ short b_lds[128 * 32];

  const int tid = threadIdx.x;
  const int lane = tid & 63, wv = tid >> 6;
  const int wr = wv >> 1, wc = wv & 1;
  const int fr = lane & 15, fg = lane >> 4;

  f32x4 acc[4][4];
#pragma unroll
  for (int i = 0; i < 4; ++i)
#pragma unroll
    for (int j = 0; j < 4; ++j) acc[i][j] = (f32x4){0.f, 0.f, 0.f, 0.f};

  const int ar = tid >> 2;          // A staging row (0..63) per round
  const int ak = (tid & 3) * 8;     // A staging k-offset (elems)

  for (int k0 = 0; k0 < 512; k0 += 32) {
    __syncthreads();
    // B tile [128 n][32 k] via global_load_lds from Wt (zero VALU)
#pragma unroll
    for (int i = 0; i < 2; ++i) {
      const int n = i * 64 + wv * 16 + (lane >> 2);
      gl_lds16(Wz + (size_t)(col0 + n) * 512 + k0 + (lane & 3) * 8,
               &b_lds[(i * 64 + wv * 16) * 32 + lane * 8]);
    }
    // A tile [128 m][32 k]: fp32 -> regs -> cvt_pk -> LDS
#pragma unroll
    for (int jj = 0; jj < 2; ++jj) {
      const int r = jj * 64 + ar;
      const f32x4* ap = (const f32x4*)(X + (size_t)(row0 + r) * 512 + k0 + ak);
      f32x4 f0 = ap[0], f1 = ap[1];
      uint4v s;
      s[0] = pk2(f0[0], f0[1]); s[1] = pk2(f0[2], f0[3]);
      s[2] = pk2(f1[0], f1[1]); s[3] = pk2(f1[2], f1[3]);
      *(uint4v*)&a_lds[r * 32 + ak] = s;
    }
    __syncthreads();

    short8 af[4], bfr[4];
#pragma unroll
    for (int mi = 0; mi < 4; ++mi)
      af[mi] = *(const short8*)&a_lds[(wr * 64 + mi * 16 + fr) * 32 + fg * 8];
#pragma unroll
    for (int ni = 0; ni < 4; ++ni)
      bfr[ni] = *(const short8*)&b_lds[(wc * 64 + ni * 16 + fr) * 32 + fg * 8];
#pragma unroll
    for (int mi = 0; mi < 4; ++mi)
#pragma unroll
      for (int ni = 0; ni < 4; ++ni)
        acc[mi][ni] = __builtin_amdgcn_mfma_f32_16x16x32_bf16(af[mi], bfr[ni], acc[mi][ni], 0, 0, 0);
  }

#pragma unroll
  for (int ni = 0; ni < 4; ++ni) {
    const int gc = col0 + wc * 64 + ni * 16 + fr;
    const float bv = bias[gc];
#pragma unroll
    for (int mi = 0; mi < 4; ++mi) {
#pragma unroll
      for (int r = 0; r < 4; ++r) {
        const int gr = row0 + wr * 64 + mi * 16 + fg * 4 + r;
        const short b = f2bf(acc[mi][ni][r] + bv);
        if (z == 0) {
          const int h = gc >> 5, j = gc & 31;
          qbuf[(size_t)gr * QSTRIDE + h * 34 + 2 + j] = b;
        } else if (z == 1) {
          kp[(size_t)gr * 512 + gc] = b;
        } else {
          vp[(size_t)gr * 512 + gc] = b;
        }
      }
    }
  }
}

// ---------------- pos columns + zero pad of qbuf ----------------------------
__global__ __launch_bounds__(256) void fillpos_kernel(
    const float* __restrict__ pos, short* __restrict__ qbuf)
{
  const int i = blockIdx.x * 256 + threadIdx.x;   // 0..32767
  const short b0 = f2bf(pos[(size_t)i * 2]);
  const short b1 = f2bf(pos[(size_t)i * 2 + 1]);
  short* row = qbuf + (size_t)i * QSTRIDE;
#pragma unroll
  for (int h = 0; h < 16; ++h) { row[h * 34] = b0; row[h * 34 + 1] = b1; }
  const short8 zz = (short8){0,0,0,0,0,0,0,0};
#pragma unroll
  for (int p = 0; p < 4; ++p) ((short8*)(row + 544))[p] = zz;
}

// ---------------- LN + ktv accumulation ------------------------------------
#define SC 256
#define TP 264

__global__ __launch_bounds__(256) void ktv_kernel(
    const short* __restrict__ kp, const short* __restrict__ vp,
    const float* __restrict__ pos,
    const float* __restrict__ lnwK, const float* __restrict__ lnbK,
    const float* __restrict__ lnwV, const float* __restrict__ lnbV,
    float* __restrict__ ktv)
{
  const int nh = blockIdx.y;
  const int n = nh >> 4, h = nh & 15;
  const int s0 = blockIdx.x * SC;
  const int tid = threadIdx.x;

  __shared__ short klds[48 * TP];
  __shared__ short vlds[48 * TP];
  __shared__ float lw[2][32], lb[2][32];

  if (tid < 32) {
    lw[0][tid] = lnwK[h * 32 + tid]; lb[0][tid] = lnbK[h * 32 + tid];
    lw[1][tid] = lnwV[h * 32 + tid]; lb[1][tid] = lnbV[h * 32 + tid];
  }
  __syncthreads();

  const size_t rowix = (size_t)n * 8192 + (s0 + tid);
  {
    const short8* src = (const short8*)(kp + rowix * 512 + h * 32);
    short8 r0 = src[0], r1 = src[1], r2 = src[2], r3 = src[3];
    float x[32];
#pragma unroll
    for (int i = 0; i < 8; ++i) { x[i] = bf2f(r0[i]); x[8+i] = bf2f(r1[i]); x[16+i] = bf2f(r2[i]); x[24+i] = bf2f(r3[i]); }
    float mu = 0.f;
#pragma unroll
    for (int i = 0; i < 32; ++i) mu += x[i];
    mu *= (1.f / 32.f);
    float var = 0.f;
#pragma unroll
    for (int i = 0; i < 32; ++i) { float d = x[i] - mu; var += d * d; }
    var *= (1.f / 32.f);
    const float rstd = rsqrtf(var + 1e-5f);
#pragma unroll
    for (int d = 0; d < 32; ++d)
      klds[d * TP + tid] = f2bf((x[d] - mu) * rstd * lw[0][d] + lb[0][d]);
  }
  {
    const short8* src = (const short8*)(vp + rowix * 512 + h * 32);
    short8 r0 = src[0], r1 = src[1], r2 = src[2], r3 = src[3];
    float x[32];
#pragma unroll
    for (int i = 0; i < 8; ++i) { x[i] = bf2f(r0[i]); x[8+i] = bf2f(r1[i]); x[16+i] = bf2f(r2[i]); x[24+i] = bf2f(r3[i]); }
    float mu = 0.f;
#pragma unroll
    for (int i = 0; i < 32; ++i) mu += x[i];
    mu *= (1.f / 32.f);
    float var = 0.f;
#pragma unroll
    for (int i = 0; i < 32; ++i) { float d = x[i] - mu; var += d * d; }
    var *= (1.f / 32.f);
    const float rstd = rsqrtf(var + 1e-5f);
#pragma unroll
    for (int d = 0; d < 32; ++d)
      vlds[d * TP + tid] = f2bf((x[d] - mu) * rstd * lw[1][d] + lb[1][d]);
  }
  {
    const short p0 = f2bf(pos[rowix * 2]);
    const short p1 = f2bf(pos[rowix * 2 + 1]);
    klds[32 * TP + tid] = p0; klds[33 * TP + tid] = p1;
    vlds[32 * TP + tid] = p0; vlds[33 * TP + tid] = p1;
  }
  __syncthreads();

  const int wv = tid >> 6, lane = tid & 63;
  if (wv < 3) {
    const int fr = lane & 15, fg = lane >> 4;
    f32x4 acc[3];
#pragma unroll
    for (int i = 0; i < 3; ++i) acc[i] = (f32x4){0.f, 0.f, 0.f, 0.f};
    for (int kk = 0; kk < SC; kk += 32) {
      short8 a = *(const short8*)&klds[(wv * 16 + fr) * TP + kk + fg * 8];
#pragma unroll
      for (int ni = 0; ni < 3; ++ni) {
        short8 b = *(const short8*)&vlds[(ni * 16 + fr) * TP + kk + fg * 8];
        acc[ni] = __builtin_amdgcn_mfma_f32_16x16x32_bf16(a, b, acc[ni], 0, 0, 0);
      }
    }
#pragma unroll
    for (int ni = 0; ni < 3; ++ni) {
      const int ei = ni * 16 + fr;
      if (ei < 34) {
        const int er = (ei < 32) ? ei + 2 : ei - 32;
#pragma unroll
        for (int r = 0; r < 4; ++r) {
          const int di = wv * 16 + fg * 4 + r;
          if (di < 34) {
            const int dr = (di < 32) ? di + 2 : di - 32;
            atomicAdd(&ktv[((size_t)nh * 34 + dr) * 34 + er], acc[ni][r]);
          }
        }
      }
    }
  }
}

// -------- Mt[n][o][c] = sum_e ktv[n,h(c),d(c),e]/S * fcW[o][h*34+e], bf16 ---
__global__ __launch_bounds__(256) void mmk_kernel(
    const float* __restrict__ ktv, const float* __restrict__ fcW,
    short* __restrict__ Mt)
{
  const int n = blockIdx.y;
  const int o = blockIdx.x;             // 0..511
  __shared__ float w[544];
  __shared__ float kv[16 * 34 * 34];
  for (int i = threadIdx.x; i < 544; i += 256) w[i] = fcW[(size_t)o * 544 + i];
  for (int i = threadIdx.x; i < 16 * 34 * 34; i += 256)
    kv[i] = ktv[(size_t)n * 16 * 34 * 34 + i] * (1.0f / 8192.0f);
  __syncthreads();
  for (int c = threadIdx.x; c < QSTRIDE; c += 256) {
    short val = 0;
    if (c < 544) {
      const int h = c / 34, d = c - h * 34;
      const float* kr = &kv[(h * 34 + d) * 34];
      const float* wr = &w[h * 34];
      float acc = 0.f;
#pragma unroll
      for (int e = 0; e < 34; ++e) acc += kr[e] * wr[e];
      val = f2bf(acc);
    }
    Mt[((size_t)n * 512 + o) * QSTRIDE + c] = val;
  }
}

// ---------------- final GEMM: out[n] = qbuf[n] @ Mt[n]^T + fc_b -------------
__global__ __launch_bounds__(256) void fgemm_kernel(
    const short* __restrict__ qbuf, const short* __restrict__ Mt,
    const float* __restrict__ fcb, float* __restrict__ out)
{
  const int n = blockIdx.z;
  const int row0 = blockIdx.y * 128;
  const int col0 = blockIdx.x * 128;

  const short* A = qbuf + (size_t)n * 8192 * QSTRIDE;
  const short* B = Mt + (size_t)n * 512 * QSTRIDE;

  __shared__ short a_lds[128 * 32];
  __shared__ short b_lds[128 * 32];

  const int tid = threadIdx.x;
  const int lane = tid & 63, wv = tid >> 6;
  const int wr = wv >> 1, wc = wv & 1;
  const int fr = lane & 15, fg = lane >> 4;

  f32x4 acc[4][4];
#pragma unroll
  for (int i = 0; i < 4; ++i)
#pragma unroll
    for (int j = 0; j < 4; ++j) acc[i][j] = (f32x4){0.f, 0.f, 0.f, 0.f};

  for (int k0 = 0; k0 < QSTRIDE; k0 += 32) {   // 18 steps
    __syncthreads();
#pragma unroll
    for (int i = 0; i < 2; ++i) {
      const int r = i * 64 + wv * 16 + (lane >> 2);
      gl_lds16(A + (size_t)(row0 + r) * QSTRIDE + k0 + (lane & 3) * 8,
               &a_lds[(i * 64 + wv * 16) * 32 + lane * 8]);
      gl_lds16(B + (size_t)(col0 + r) * QSTRIDE + k0 + (lane & 3) * 8,
               &b_lds[(i * 64 + wv * 16) * 32 + lane * 8]);
    }
    __syncthreads();

    short8 af[4], bfr[4];
#pragma unroll
    for (int mi = 0; mi < 4; ++mi)
      af[mi] = *(const short8*)&a_lds[(wr * 64 + mi * 16 + fr) * 32 + fg * 8];
#pragma unroll
    for (int ni = 0; ni < 4; ++ni)
      bfr[ni] = *(const short8*)&b_lds[(wc * 64 + ni * 16 + fr) * 32 + fg * 8];
#pragma unroll
    for (int mi = 0; mi < 4; ++mi)
#pragma unroll
      for (int ni = 0; ni < 4; ++ni)
        acc[mi][ni] = __builtin_amdgcn_mfma_f32_16x16x32_bf16(af[mi], bfr[ni], acc[mi][ni], 0, 0, 0);
  }

#pragma unroll
  for (int ni = 0; ni < 4; ++ni) {
    const int gc = col0 + wc * 64 + ni * 16 + fr;
    const float bv = fcb[gc];
#pragma unroll
    for (int mi = 0; mi < 4; ++mi)
#pragma unroll
      for (int r = 0; r < 4; ++r) {
        const int gr = row0 + wr * 64 + mi * 16 + fg * 4 + r;
        out[((size_t)n * 8192 + gr) * 512 + gc] = acc[mi][ni][r] + bv;
      }
  }
}

// ---------------------------------------------------------------------------
extern "C" void kernel_launch(void* const* d_in, const int* in_sizes, int n_in,
                              void* d_out, int out_size, void* d_ws, size_t ws_size,
                              hipStream_t stream) {
  const float* Q    = (const float*)d_in[0];
  const float* Kin  = (const float*)d_in[1];
  const float* Vin  = (const float*)d_in[2];
  const float* pos  = (const float*)d_in[3];
  const float* WQ   = (const float*)d_in[4];
  const float* WK   = (const float*)d_in[5];
  const float* WV   = (const float*)d_in[6];
  const float* bQ   = (const float*)d_in[7];
  const float* bK   = (const float*)d_in[8];
  const float* bV   = (const float*)d_in[9];
  const float* lnwK = (const float*)d_in[10];
  const float* lnbK = (const float*)d_in[11];
  const float* lnwV = (const float*)d_in[12];
  const float* lnbV = (const float*)d_in[13];
  const float* fcW  = (const float*)d_in[14];
  const float* fcb  = (const float*)d_in[15];

  char* ws = (char*)d_ws;
  const size_t QBUF_B = (size_t)4 * 8192 * QSTRIDE * 2;  // 37,748,736
  const size_t KP_B   = (size_t)4 * 8192 * 512 * 2;      // 33,554,432
  const size_t KTV_B  = (size_t)64 * 34 * 34 * 4;        //    295,936
  const size_t MT_B   = (size_t)4 * 512 * QSTRIDE * 2;   //  2,359,296
  short* qbuf = (short*)ws;
  short* kp   = (short*)(ws + QBUF_B);
  short* vp   = (short*)(ws + QBUF_B + KP_B);
  float* ktv  = (float*)(ws + QBUF_B + 2 * KP_B);
  short* Mt   = (short*)(ws + QBUF_B + 2 * KP_B + KTV_B);
  short* Wt   = (short*)(ws + QBUF_B + 2 * KP_B + KTV_B + MT_B);

  (void)hipMemsetAsync(ktv, 0, KTV_B, stream);
  hipLaunchKernelGGL(wt_kernel, dim3(8, 8, 3), dim3(256), 0, stream, WQ, WK, WV, Wt);
  hipLaunchKernelGGL(proj_kernel, dim3(4, 256, 3), dim3(256), 0, stream,
                     Q, Kin, Vin, Wt, bQ, bK, bV, qbuf, kp, vp);
  hipLaunchKernelGGL(fillpos_kernel, dim3(128), dim3(256), 0, stream, pos, qbuf);
  hipLaunchKernelGGL(ktv_kernel, dim3(32, 64), dim3(256), 0, stream,
                     kp, vp, pos, lnwK, lnbK, lnwV, lnbV, ktv);
  hipLaunchKernelGGL(mmk_kernel, dim3(512, 4), dim3(256), 0, stream, ktv, fcW, Mt);
  hipLaunchKernelGGL(fgemm_kernel, dim3(4, 64, 4), dim3(256), 0, stream,
                     qbuf, Mt, fcb, (float*)d_out);
}

// Round 4
// 255.327 us; speedup vs baseline: 1.2278x; 1.1320x over previous
//
#include <hip/hip_runtime.h>
#include <hip/hip_bf16.h>

typedef short short8 __attribute__((ext_vector_type(8)));
typedef float f32x4 __attribute__((ext_vector_type(4)));
typedef unsigned int uint4v __attribute__((ext_vector_type(4)));

__device__ __forceinline__ short f2bf(float f) {
  unsigned u = __builtin_bit_cast(unsigned, f);
  u += 0x7fffu + ((u >> 16) & 1u);          // RNE
  return (short)(u >> 16);
}
__device__ __forceinline__ float bf2f(short s) {
  unsigned u = ((unsigned)(unsigned short)s) << 16;
  return __builtin_bit_cast(float, u);
}
__device__ __forceinline__ unsigned pk2(float a, float b) {
  __hip_bfloat162 h = __float22bfloat162_rn(float2{a, b});
  unsigned u;
  __builtin_memcpy(&u, &h, 4);
  return u;
}
__device__ __forceinline__ void gl_lds16(const void* g, void* l) {
  __builtin_amdgcn_global_load_lds(
      (const __attribute__((address_space(1))) unsigned int*)g,
      (__attribute__((address_space(3))) unsigned int*)l, 16, 0, 0);
}

#define QSTRIDE 576

// ---------------- W transpose + bf16 convert: Wt[z][n][k] -------------------
__global__ __launch_bounds__(256) void wt_kernel(
    const float* __restrict__ WQ, const float* __restrict__ WK, const float* __restrict__ WV,
    short* __restrict__ Wt)
{
  const int z = blockIdx.z;
  const float* W = (z == 0) ? WQ : (z == 1) ? WK : WV;
  short* o = Wt + (size_t)z * 512 * 512;
  __shared__ short t[64][65];
  const int k0 = blockIdx.y * 64, n0 = blockIdx.x * 64;
  const int c = threadIdx.x & 63, rb = threadIdx.x >> 6;
#pragma unroll
  for (int p = 0; p < 16; ++p) {
    const int kk = p * 4 + rb;
    t[kk][c] = f2bf(W[(size_t)(k0 + kk) * 512 + n0 + c]);
  }
  __syncthreads();
#pragma unroll
  for (int p = 0; p < 16; ++p) {
    const int nn = p * 4 + rb;
    o[(size_t)(n0 + nn) * 512 + k0 + c] = t[c][nn];
  }
}

// ---------------- Projection GEMM, double-buffered pipeline -----------------
// logical block id: z (0..2), row0 (0..255)*128, col0 (0..3)*128
__global__ __launch_bounds__(256) void proj_kernel(
    const float* __restrict__ Q, const float* __restrict__ Kin, const float* __restrict__ Vin,
    const short* __restrict__ Wt,
    const float* __restrict__ bQ, const float* __restrict__ bK, const float* __restrict__ bV,
    short* __restrict__ qbuf, short* __restrict__ kp, short* __restrict__ vp)
{
  // chunked XCD swizzle over 3072 blocks: XCD x gets logical [x*384,(x+1)*384)
  const int phys = blockIdx.x;
  const int log_ = (phys & 7) * 384 + (phys >> 3);
  const int z = log_ >> 10;
  const int rem = log_ & 1023;
  const int row0 = (rem >> 2) * 128;
  const int col0 = (rem & 3) * 128;

  const float* X    = (z == 0) ? Q  : (z == 1) ? Kin : Vin;
  const float* bias = (z == 0) ? bQ : (z == 1) ? bK  : bV;
  const short* Wz   = Wt + (size_t)z * 512 * 512;

  __shared__ short a_lds[2][128 * 32];
  __shared__ short b_lds[2][128 * 32];

  const int tid = threadIdx.x;
  const int lane = tid & 63, wv = tid >> 6;
  const int wr = wv >> 1, wc = wv & 1;
  const int fr = lane & 15, fg = lane >> 4;

  f32x4 acc[4][4];
#pragma unroll
  for (int i = 0; i < 4; ++i)
#pragma unroll
    for (int j = 0; j < 4; ++j) acc[i][j] = (f32x4){0.f, 0.f, 0.f, 0.f};

  const int ar = tid >> 2;          // A staging row (0..63) per half
  const int ak = (tid & 3) * 8;     // A staging k-offset (elems)
  // B staging: wave wv stages rows [i*64+wv*16, +16), lane covers (row, 8k-seg)
  const int bn0 = wv * 16 + (lane >> 2);
  const int bk0 = (lane & 3) * 8;

  // ---- prologue: stage tile 0 into buf 0
  {
#pragma unroll
    for (int i = 0; i < 2; ++i)
      gl_lds16(Wz + (size_t)(col0 + i * 64 + bn0) * 512 + bk0,
               &b_lds[0][(i * 64 + wv * 16) * 32 + lane * 8]);
#pragma unroll
    for (int jj = 0; jj < 2; ++jj) {
      const int r = jj * 64 + ar;
      const f32x4* ap = (const f32x4*)(X + (size_t)(row0 + r) * 512 + ak);
      f32x4 f0 = ap[0], f1 = ap[1];
      uint4v s;
      s[0] = pk2(f0[0], f0[1]); s[1] = pk2(f0[2], f0[3]);
      s[2] = pk2(f1[0], f1[1]); s[3] = pk2(f1[2], f1[3]);
      *(uint4v*)&a_lds[0][r * 32 + ak] = s;
    }
  }
  __syncthreads();

  for (int t = 0; t < 16; ++t) {
    const int cur = t & 1;
    const short* acur = a_lds[cur];
    const short* bcur = b_lds[cur];
    f32x4 p0, p1, p2, p3;
    const bool pf = (t < 15);
    if (pf) {                       // issue next-tile loads FIRST (latency hides under MFMA)
      const int k1 = (t + 1) * 32;
      short* bn = b_lds[cur ^ 1];
#pragma unroll
      for (int i = 0; i < 2; ++i)
        gl_lds16(Wz + (size_t)(col0 + i * 64 + bn0) * 512 + k1 + bk0,
                 &bn[(i * 64 + wv * 16) * 32 + lane * 8]);
      const f32x4* ap0 = (const f32x4*)(X + (size_t)(row0 + ar) * 512 + k1 + ak);
      p0 = ap0[0]; p1 = ap0[1];
      const f32x4* ap1 = (const f32x4*)(X + (size_t)(row0 + 64 + ar) * 512 + k1 + ak);
      p2 = ap1[0]; p3 = ap1[1];
    }

    short8 af[4], bfr[4];
#pragma unroll
    for (int mi = 0; mi < 4; ++mi)
      af[mi] = *(const short8*)&acur[(wr * 64 + mi * 16 + fr) * 32 + fg * 8];
#pragma unroll
    for (int ni = 0; ni < 4; ++ni)
      bfr[ni] = *(const short8*)&bcur[(wc * 64 + ni * 16 + fr) * 32 + fg * 8];
#pragma unroll
    for (int mi = 0; mi < 4; ++mi)
#pragma unroll
      for (int ni = 0; ni < 4; ++ni)
        acc[mi][ni] = __builtin_amdgcn_mfma_f32_16x16x32_bf16(af[mi], bfr[ni], acc[mi][ni], 0, 0, 0);

    if (pf) {                       // convert + write A(t+1); waits vmcnt after compute
      short* an = a_lds[cur ^ 1];
      uint4v s;
      s[0] = pk2(p0[0], p0[1]); s[1] = pk2(p0[2], p0[3]);
      s[2] = pk2(p1[0], p1[1]); s[3] = pk2(p1[2], p1[3]);
      *(uint4v*)&an[ar * 32 + ak] = s;
      s[0] = pk2(p2[0], p2[1]); s[1] = pk2(p2[2], p2[3]);
      s[2] = pk2(p3[0], p3[1]); s[3] = pk2(p3[2], p3[3]);
      *(uint4v*)&an[(64 + ar) * 32 + ak] = s;
    }
    __syncthreads();
  }

#pragma unroll
  for (int ni = 0; ni < 4; ++ni) {
    const int gc = col0 + wc * 64 + ni * 16 + fr;
    const float bv = bias[gc];
#pragma unroll
    for (int mi = 0; mi < 4; ++mi) {
#pragma unroll
      for (int r = 0; r < 4; ++r) {
        const int gr = row0 + wr * 64 + mi * 16 + fg * 4 + r;
        const short b = f2bf(acc[mi][ni][r] + bv);
        if (z == 0) {
          const int h = gc >> 5, j = gc & 31;
          qbuf[(size_t)gr * QSTRIDE + h * 34 + 2 + j] = b;
        } else if (z == 1) {
          kp[(size_t)gr * 512 + gc] = b;
        } else {
          vp[(size_t)gr * 512 + gc] = b;
        }
      }
    }
  }
}

// ---------------- pos columns + zero pad of qbuf ----------------------------
__global__ __launch_bounds__(256) void fillpos_kernel(
    const float* __restrict__ pos, short* __restrict__ qbuf)
{
  const int i = blockIdx.x * 256 + threadIdx.x;
  const short b0 = f2bf(pos[(size_t)i * 2]);
  const short b1 = f2bf(pos[(size_t)i * 2 + 1]);
  short* row = qbuf + (size_t)i * QSTRIDE;
#pragma unroll
  for (int h = 0; h < 16; ++h) { row[h * 34] = b0; row[h * 34 + 1] = b1; }
  const short8 zz = (short8){0,0,0,0,0,0,0,0};
#pragma unroll
  for (int p = 0; p < 4; ++p) ((short8*)(row + 544))[p] = zz;
}

// ---------------- LN + ktv accumulation ------------------------------------
#define SC 256
#define TP 264

__global__ __launch_bounds__(256) void ktv_kernel(
    const short* __restrict__ kp, const short* __restrict__ vp,
    const float* __restrict__ pos,
    const float* __restrict__ lnwK, const float* __restrict__ lnbK,
    const float* __restrict__ lnwV, const float* __restrict__ lnbV,
    float* __restrict__ ktv)
{
  const int nh = blockIdx.y;
  const int n = nh >> 4, h = nh & 15;
  const int s0 = blockIdx.x * SC;
  const int tid = threadIdx.x;

  __shared__ short klds[48 * TP];
  __shared__ short vlds[48 * TP];
  __shared__ float lw[2][32], lb[2][32];

  if (tid < 32) {
    lw[0][tid] = lnwK[h * 32 + tid]; lb[0][tid] = lnbK[h * 32 + tid];
    lw[1][tid] = lnwV[h * 32 + tid]; lb[1][tid] = lnbV[h * 32 + tid];
  }
  __syncthreads();

  const size_t rowix = (size_t)n * 8192 + (s0 + tid);
  {
    const short8* src = (const short8*)(kp + rowix * 512 + h * 32);
    short8 r0 = src[0], r1 = src[1], r2 = src[2], r3 = src[3];
    float x[32];
#pragma unroll
    for (int i = 0; i < 8; ++i) { x[i] = bf2f(r0[i]); x[8+i] = bf2f(r1[i]); x[16+i] = bf2f(r2[i]); x[24+i] = bf2f(r3[i]); }
    float mu = 0.f;
#pragma unroll
    for (int i = 0; i < 32; ++i) mu += x[i];
    mu *= (1.f / 32.f);
    float var = 0.f;
#pragma unroll
    for (int i = 0; i < 32; ++i) { float d = x[i] - mu; var += d * d; }
    var *= (1.f / 32.f);
    const float rstd = rsqrtf(var + 1e-5f);
#pragma unroll
    for (int d = 0; d < 32; ++d)
      klds[d * TP + tid] = f2bf((x[d] - mu) * rstd * lw[0][d] + lb[0][d]);
  }
  {
    const short8* src = (const short8*)(vp + rowix * 512 + h * 32);
    short8 r0 = src[0], r1 = src[1], r2 = src[2], r3 = src[3];
    float x[32];
#pragma unroll
    for (int i = 0; i < 8; ++i) { x[i] = bf2f(r0[i]); x[8+i] = bf2f(r1[i]); x[16+i] = bf2f(r2[i]); x[24+i] = bf2f(r3[i]); }
    float mu = 0.f;
#pragma unroll
    for (int i = 0; i < 32; ++i) mu += x[i];
    mu *= (1.f / 32.f);
    float var = 0.f;
#pragma unroll
    for (int i = 0; i < 32; ++i) { float d = x[i] - mu; var += d * d; }
    var *= (1.f / 32.f);
    const float rstd = rsqrtf(var + 1e-5f);
#pragma unroll
    for (int d = 0; d < 32; ++d)
      vlds[d * TP + tid] = f2bf((x[d] - mu) * rstd * lw[1][d] + lb[1][d]);
  }
  {
    const short p0 = f2bf(pos[rowix * 2]);
    const short p1 = f2bf(pos[rowix * 2 + 1]);
    klds[32 * TP + tid] = p0; klds[33 * TP + tid] = p1;
    vlds[32 * TP + tid] = p0; vlds[33 * TP + tid] = p1;
  }
  __syncthreads();

  const int wv = tid >> 6, lane = tid & 63;
  if (wv < 3) {
    const int fr = lane & 15, fg = lane >> 4;
    f32x4 acc[3];
#pragma unroll
    for (int i = 0; i < 3; ++i) acc[i] = (f32x4){0.f, 0.f, 0.f, 0.f};
    for (int kk = 0; kk < SC; kk += 32) {
      short8 a = *(const short8*)&klds[(wv * 16 + fr) * TP + kk + fg * 8];
#pragma unroll
      for (int ni = 0; ni < 3; ++ni) {
        short8 b = *(const short8*)&vlds[(ni * 16 + fr) * TP + kk + fg * 8];
        acc[ni] = __builtin_amdgcn_mfma_f32_16x16x32_bf16(a, b, acc[ni], 0, 0, 0);
      }
    }
#pragma unroll
    for (int ni = 0; ni < 3; ++ni) {
      const int ei = ni * 16 + fr;
      if (ei < 34) {
        const int er = (ei < 32) ? ei + 2 : ei - 32;
#pragma unroll
        for (int r = 0; r < 4; ++r) {
          const int di = wv * 16 + fg * 4 + r;
          if (di < 34) {
            const int dr = (di < 32) ? di + 2 : di - 32;
            atomicAdd(&ktv[((size_t)nh * 34 + dr) * 34 + er], acc[ni][r]);
          }
        }
      }
    }
  }
}

// -------- Mt[n][o][c] = sum_e ktv[n,h(c),d(c),e]/S * fcW[o][h*34+e], bf16 ---
__global__ __launch_bounds__(256) void mmk_kernel(
    const float* __restrict__ ktv, const float* __restrict__ fcW,
    short* __restrict__ Mt)
{
  const int n = blockIdx.y;
  const int o = blockIdx.x;
  __shared__ float w[544];
  __shared__ float kv[16 * 34 * 34];
  for (int i = threadIdx.x; i < 544; i += 256) w[i] = fcW[(size_t)o * 544 + i];
  for (int i = threadIdx.x; i < 16 * 34 * 34; i += 256)
    kv[i] = ktv[(size_t)n * 16 * 34 * 34 + i] * (1.0f / 8192.0f);
  __syncthreads();
  for (int c = threadIdx.x; c < QSTRIDE; c += 256) {
    short val = 0;
    if (c < 544) {
      const int h = c / 34, d = c - h * 34;
      const float* kr = &kv[(h * 34 + d) * 34];
      const float* wr = &w[h * 34];
      float acc = 0.f;
#pragma unroll
      for (int e = 0; e < 34; ++e) acc += kr[e] * wr[e];
      val = f2bf(acc);
    }
    Mt[((size_t)n * 512 + o) * QSTRIDE + c] = val;
  }
}

// ---------------- final GEMM: out[n] = qbuf[n] @ Mt[n]^T + fc_b -------------
// logical: n (0..3), row0 (0..63)*128, col0 (0..3)*128 -> 1024 blocks
__global__ __launch_bounds__(256) void fgemm_kernel(
    const short* __restrict__ qbuf, const short* __restrict__ Mt,
    const float* __restrict__ fcb, float* __restrict__ out)
{
  const int phys = blockIdx.x;
  const int log_ = (phys & 7) * 128 + (phys >> 3);
  const int n = log_ >> 8;
  const int rem = log_ & 255;
  const int row0 = (rem >> 2) * 128;
  const int col0 = (rem & 3) * 128;

  const short* A = qbuf + (size_t)n * 8192 * QSTRIDE;
  const short* B = Mt + (size_t)n * 512 * QSTRIDE;

  __shared__ short a_lds[2][128 * 32];
  __shared__ short b_lds[2][128 * 32];

  const int tid = threadIdx.x;
  const int lane = tid & 63, wv = tid >> 6;
  const int wr = wv >> 1, wc = wv & 1;
  const int fr = lane & 15, fg = lane >> 4;

  const int sn0 = wv * 16 + (lane >> 2);     // staging row within 64-half
  const int sk0 = (lane & 3) * 8;            // staging k-offset

  f32x4 acc[4][4];
#pragma unroll
  for (int i = 0; i < 4; ++i)
#pragma unroll
    for (int j = 0; j < 4; ++j) acc[i][j] = (f32x4){0.f, 0.f, 0.f, 0.f};

  // prologue: tile 0 into buf 0
#pragma unroll
  for (int i = 0; i < 2; ++i) {
    gl_lds16(A + (size_t)(row0 + i * 64 + sn0) * QSTRIDE + sk0,
             &a_lds[0][(i * 64 + wv * 16) * 32 + lane * 8]);
    gl_lds16(B + (size_t)(col0 + i * 64 + sn0) * QSTRIDE + sk0,
             &b_lds[0][(i * 64 + wv * 16) * 32 + lane * 8]);
  }
  __syncthreads();

  for (int t = 0; t < 18; ++t) {
    const int cur = t & 1;
    if (t < 17) {
      const int k1 = (t + 1) * 32;
      short* an = a_lds[cur ^ 1];
      short* bn = b_lds[cur ^ 1];
#pragma unroll
      for (int i = 0; i < 2; ++i) {
        gl_lds16(A + (size_t)(row0 + i * 64 + sn0) * QSTRIDE + k1 + sk0,
                 &an[(i * 64 + wv * 16) * 32 + lane * 8]);
        gl_lds16(B + (size_t)(col0 + i * 64 + sn0) * QSTRIDE + k1 + sk0,
                 &bn[(i * 64 + wv * 16) * 32 + lane * 8]);
      }
    }
    const short* acur = a_lds[cur];
    const short* bcur = b_lds[cur];
    short8 af[4], bfr[4];
#pragma unroll
    for (int mi = 0; mi < 4; ++mi)
      af[mi] = *(const short8*)&acur[(wr * 64 + mi * 16 + fr) * 32 + fg * 8];
#pragma unroll
    for (int ni = 0; ni < 4; ++ni)
      bfr[ni] = *(const short8*)&bcur[(wc * 64 + ni * 16 + fr) * 32 + fg * 8];
#pragma unroll
    for (int mi = 0; mi < 4; ++mi)
#pragma unroll
      for (int ni = 0; ni < 4; ++ni)
        acc[mi][ni] = __builtin_amdgcn_mfma_f32_16x16x32_bf16(af[mi], bfr[ni], acc[mi][ni], 0, 0, 0);
    __syncthreads();
  }

#pragma unroll
  for (int ni = 0; ni < 4; ++ni) {
    const int gc = col0 + wc * 64 + ni * 16 + fr;
    const float bv = fcb[gc];
#pragma unroll
    for (int mi = 0; mi < 4; ++mi)
#pragma unroll
      for (int r = 0; r < 4; ++r) {
        const int gr = row0 + wr * 64 + mi * 16 + fg * 4 + r;
        out[((size_t)n * 8192 + gr) * 512 + gc] = acc[mi][ni][r] + bv;
      }
  }
}

// ---------------------------------------------------------------------------
extern "C" void kernel_launch(void* const* d_in, const int* in_sizes, int n_in,
                              void* d_out, int out_size, void* d_ws, size_t ws_size,
                              hipStream_t stream) {
  const float* Q    = (const float*)d_in[0];
  const float* Kin  = (const float*)d_in[1];
  const float* Vin  = (const float*)d_in[2];
  const float* pos  = (const float*)d_in[3];
  const float* WQ   = (const float*)d_in[4];
  const float* WK   = (const float*)d_in[5];
  const float* WV   = (const float*)d_in[6];
  const float* bQ   = (const float*)d_in[7];
  const float* bK   = (const float*)d_in[8];
  const float* bV   = (const float*)d_in[9];
  const float* lnwK = (const float*)d_in[10];
  const float* lnbK = (const float*)d_in[11];
  const float* lnwV = (const float*)d_in[12];
  const float* lnbV = (const float*)d_in[13];
  const float* fcW  = (const float*)d_in[14];
  const float* fcb  = (const float*)d_in[15];

  char* ws = (char*)d_ws;
  const size_t QBUF_B = (size_t)4 * 8192 * QSTRIDE * 2;
  const size_t KP_B   = (size_t)4 * 8192 * 512 * 2;
  const size_t KTV_B  = (size_t)64 * 34 * 34 * 4;
  const size_t MT_B   = (size_t)4 * 512 * QSTRIDE * 2;
  short* qbuf = (short*)ws;
  short* kp   = (short*)(ws + QBUF_B);
  short* vp   = (short*)(ws + QBUF_B + KP_B);
  float* ktv  = (float*)(ws + QBUF_B + 2 * KP_B);
  short* Mt   = (short*)(ws + QBUF_B + 2 * KP_B + KTV_B);
  short* Wt   = (short*)(ws + QBUF_B + 2 * KP_B + KTV_B + MT_B);

  (void)hipMemsetAsync(ktv, 0, KTV_B, stream);
  hipLaunchKernelGGL(wt_kernel, dim3(8, 8, 3), dim3(256), 0, stream, WQ, WK, WV, Wt);
  hipLaunchKernelGGL(proj_kernel, dim3(3072), dim3(256), 0, stream,
                     Q, Kin, Vin, Wt, bQ, bK, bV, qbuf, kp, vp);
  hipLaunchKernelGGL(fillpos_kernel, dim3(128), dim3(256), 0, stream, pos, qbuf);
  hipLaunchKernelGGL(ktv_kernel, dim3(32, 64), dim3(256), 0, stream,
                     kp, vp, pos, lnwK, lnbK, lnwV, lnbV, ktv);
  hipLaunchKernelGGL(mmk_kernel, dim3(512, 4), dim3(256), 0, stream, ktv, fcW, Mt);
  hipLaunchKernelGGL(fgemm_kernel, dim3(1024), dim3(256), 0, stream,
                     qbuf, Mt, fcb, (float*)d_out);
}